// Round 1
// baseline (620.925 us; speedup 1.0000x reference)
//
#include <hip/hip_runtime.h>

// ---------------------------------------------------------------------------
// 2-layer hetero GraphSAGE: songs (NS=100000, F=128) <-> playlists (NP=20000, H=128)
// Strategy:
//   - Build CSR (both directions) per call: histogram + block-scan/atomic-base + place.
//   - Aggregation = gather (one wave per dst node), no float atomics.
//   - seg_mean is linear: apply Wl on the SMALL side (playlists) always:
//       p-out: aggregate raw songs -> Ms; p = Ms@Wl + x_p@Wr + b   (2-pair GEMM)
//       s-out: pre-transform yp = x_p@Wl; aggregate yp -> As; s = As + x_s@Wr + b
//   - fp32 vector GEMM [M,128]@[128,128], W+A tiles in LDS, 8x4 reg tile/thread.
// ---------------------------------------------------------------------------

static inline size_t ws_align(size_t x) { return (x + 255) & ~size_t(255); }

__global__ __launch_bounds__(256) void gather_play_k(
    const float* __restrict__ emb, const int* __restrict__ pid,
    float* __restrict__ xp, int np)
{
  int i = blockIdx.x * 256 + threadIdx.x;   // one float4 per thread
  int node = i >> 5, q = i & 31;
  if (node >= np) return;
  const float4* src = (const float4*)(emb + (size_t)pid[node] * 128);
  ((float4*)(xp + (size_t)node * 128))[q] = src[q];
}

__global__ __launch_bounds__(256) void hist_k(
    const int* __restrict__ es, const int* __restrict__ ep,
    int* __restrict__ cnt_s, int* __restrict__ cnt_p, int e)
{
  int i = blockIdx.x * 256 + threadIdx.x;
  if (i >= e) return;
  atomicAdd(&cnt_p[ep[i]], 1);
  atomicAdd(&cnt_s[es[i]], 1);
}

// exclusive-scan counts within a block, one global atomic per block for the base.
// (group ranges need not be in index order — any disjoint partition of [0,E) works)
__global__ __launch_bounds__(256) void base_k(
    const int* __restrict__ cnt, int* __restrict__ base,
    int* __restrict__ cur, int* __restrict__ gcounter, int n)
{
  __shared__ int sh[256];
  __shared__ int bb;
  int t = threadIdx.x;
  int i = blockIdx.x * 256 + t;
  int v = (i < n) ? cnt[i] : 0;
  sh[t] = v;
  __syncthreads();
  for (int off = 1; off < 256; off <<= 1) {
    int tv = (t >= off) ? sh[t - off] : 0;
    __syncthreads();
    sh[t] += tv;
    __syncthreads();
  }
  if (t == 255) bb = atomicAdd(gcounter, sh[255]);
  __syncthreads();
  if (i < n) {
    int e = bb + sh[t] - v;   // exclusive
    base[i] = e;
    cur[i] = e;
  }
}

__global__ __launch_bounds__(256) void place_k(
    const int* __restrict__ es, const int* __restrict__ ep,
    int* __restrict__ cur_s, int* __restrict__ cur_p,
    int* __restrict__ csr_s, int* __restrict__ csr_p, int e)
{
  int i = blockIdx.x * 256 + threadIdx.x;
  if (i >= e) return;
  int s = es[i], p = ep[i];
  csr_p[atomicAdd(&cur_p[p], 1)] = s;   // playlist-dst list holds song ids
  csr_s[atomicAdd(&cur_s[s], 1)] = p;   // song-dst list holds playlist ids
}

// one wave (64 lanes) per destination node; float2 per lane = full 128-f row.
__global__ __launch_bounds__(256) void agg_mean_k(
    const float* __restrict__ feat, const int* __restrict__ csr,
    const int* __restrict__ base, const int* __restrict__ cnt,
    float* __restrict__ out, int n)
{
  int wave = (blockIdx.x * 256 + threadIdx.x) >> 6;
  int lane = threadIdx.x & 63;
  if (wave >= n) return;
  int b = base[wave], c = cnt[wave];
  float2 a0 = {0.f, 0.f}, a1 = {0.f, 0.f};
  int i = 0;
  for (; i + 1 < c; i += 2) {
    int s0 = csr[b + i], s1 = csr[b + i + 1];
    float2 v0 = ((const float2*)(feat + (size_t)s0 * 128))[lane];
    float2 v1 = ((const float2*)(feat + (size_t)s1 * 128))[lane];
    a0.x += v0.x; a0.y += v0.y;
    a1.x += v1.x; a1.y += v1.y;
  }
  if (i < c) {
    int s0 = csr[b + i];
    float2 v0 = ((const float2*)(feat + (size_t)s0 * 128))[lane];
    a0.x += v0.x; a0.y += v0.y;
  }
  float inv = (c > 0) ? 1.0f / (float)c : 0.0f;
  float2 r;
  r.x = (a0.x + a1.x) * inv;
  r.y = (a0.y + a1.y) * inv;
  ((float2*)(out + (size_t)wave * 128))[lane] = r;
}

// C[M,128] = act( A0@W0 (+ A1@W1) (+ D) (+ bias) ), all K=128, fp32.
// block 256 = 64-row tile; thread (tx=tid&31, ty=tid>>5) owns 8 rows x 4 cols.
__global__ __launch_bounds__(256) void gemm128_k(
    const float* __restrict__ A0, const float* __restrict__ W0,
    const float* __restrict__ A1, const float* __restrict__ W1,
    const float* __restrict__ Dadd, const float* __restrict__ bias,
    float* __restrict__ C, int M, int doRelu)
{
  __shared__ float As[16][68];    // [k][row], padded
  __shared__ float Ws[16][128];   // [k][col]
  int tid = threadIdx.x;
  int tx = tid & 31, ty = tid >> 5;
  int row0 = blockIdx.x * 64;

  float acc[8][4];
#pragma unroll
  for (int i = 0; i < 8; i++)
#pragma unroll
    for (int j = 0; j < 4; j++) acc[i][j] = 0.f;

  for (int pair = 0; pair < 2; ++pair) {
    const float* A = pair ? A1 : A0;
    const float* W = pair ? W1 : W0;
    if (A == nullptr) continue;
    for (int k0 = 0; k0 < 128; k0 += 16) {
      // stage A tile (64x16, transposed into LDS) and W tile (16x128)
      int r = tid >> 2, cs = tid & 3;
      int gr = row0 + r;
      float4 av = make_float4(0.f, 0.f, 0.f, 0.f);
      if (gr < M) av = *(const float4*)(A + (size_t)gr * 128 + k0 + cs * 4);
      int wk = tid >> 4, wc = (tid & 15) * 8;
      float4 wv0 = *(const float4*)(W + (size_t)(k0 + wk) * 128 + wc);
      float4 wv1 = *(const float4*)(W + (size_t)(k0 + wk) * 128 + wc + 4);
      __syncthreads();   // previous tile's compute done before overwrite
      As[cs * 4 + 0][r] = av.x;
      As[cs * 4 + 1][r] = av.y;
      As[cs * 4 + 2][r] = av.z;
      As[cs * 4 + 3][r] = av.w;
      *(float4*)&Ws[wk][wc] = wv0;
      *(float4*)&Ws[wk][wc + 4] = wv1;
      __syncthreads();
#pragma unroll
      for (int k = 0; k < 16; k++) {
        float4 a01 = *(const float4*)&As[k][ty * 8];
        float4 a23 = *(const float4*)&As[k][ty * 8 + 4];
        float4 wv = *(const float4*)&Ws[k][tx * 4];
        float a[8] = {a01.x, a01.y, a01.z, a01.w, a23.x, a23.y, a23.z, a23.w};
        float wj[4] = {wv.x, wv.y, wv.z, wv.w};
#pragma unroll
        for (int i = 0; i < 8; i++)
#pragma unroll
          for (int j = 0; j < 4; j++) acc[i][j] = fmaf(a[i], wj[j], acc[i][j]);
      }
    }
  }

  float4 bv = make_float4(0.f, 0.f, 0.f, 0.f);
  if (bias) bv = *(const float4*)(bias + tx * 4);
#pragma unroll
  for (int i = 0; i < 8; i++) {
    int gr = row0 + ty * 8 + i;
    if (gr >= M) continue;
    float4 dv = make_float4(0.f, 0.f, 0.f, 0.f);
    if (Dadd) dv = *(const float4*)(Dadd + (size_t)gr * 128 + tx * 4);
    float o0 = acc[i][0] + bv.x + dv.x;
    float o1 = acc[i][1] + bv.y + dv.y;
    float o2 = acc[i][2] + bv.z + dv.z;
    float o3 = acc[i][3] + bv.w + dv.w;
    if (doRelu) {
      o0 = fmaxf(o0, 0.f); o1 = fmaxf(o1, 0.f);
      o2 = fmaxf(o2, 0.f); o3 = fmaxf(o3, 0.f);
    }
    *(float4*)(C + (size_t)gr * 128 + tx * 4) = make_float4(o0, o1, o2, o3);
  }
}

extern "C" void kernel_launch(void* const* d_in, const int* in_sizes, int n_in,
                              void* d_out, int out_size, void* d_ws, size_t ws_size,
                              hipStream_t stream)
{
  const float* song_x = (const float*)d_in[0];
  const int*   pid    = (const int*)d_in[1];
  const int*   e_song = (const int*)d_in[2];
  const int*   e_play = (const int*)d_in[3];
  const float* emb    = (const float*)d_in[4];
  const float* Wl1_sp = (const float*)d_in[5];
  const float* Wr1_sp = (const float*)d_in[6];
  const float* b1_sp  = (const float*)d_in[7];
  const float* Wl1_ps = (const float*)d_in[8];
  const float* Wr1_ps = (const float*)d_in[9];
  const float* b1_ps  = (const float*)d_in[10];
  const float* Wl2_sp = (const float*)d_in[11];
  const float* Wr2_sp = (const float*)d_in[12];
  const float* b2_sp  = (const float*)d_in[13];
  const float* Wl2_ps = (const float*)d_in[14];
  const float* Wr2_ps = (const float*)d_in[15];
  const float* b2_ps  = (const float*)d_in[16];

  const int NS = in_sizes[0] / 128;
  const int NP = in_sizes[1];
  const int E  = in_sizes[2];

  // ---- workspace layout ----
  char* w = (char*)d_ws;
  auto alloc = [&](size_t bytes) { char* p = w; w += ws_align(bytes); return p; };
  float* x_play = (float*)alloc((size_t)NP * 128 * 4);
  float* Ms     = (float*)alloc((size_t)NP * 128 * 4);   // reused layer1/layer2
  float* yp     = (float*)alloc((size_t)NP * 128 * 4);   // reused layer1/layer2
  float* p1     = (float*)alloc((size_t)NP * 128 * 4);
  float* As     = (float*)alloc((size_t)NS * 128 * 4);   // reused layer1/layer2
  float* s1     = (float*)alloc((size_t)NS * 128 * 4);
  // zeroed region: cnt_p | cnt_s | gcnt(2), contiguous
  int* cnt_p = (int*)alloc(((size_t)NP + NS + 2) * 4);
  int* cnt_s = cnt_p + NP;
  int* gcnt  = cnt_s + NS;
  int* base_p = (int*)alloc((size_t)NP * 4);
  int* cur_p  = (int*)alloc((size_t)NP * 4);
  int* base_s = (int*)alloc((size_t)NS * 4);
  int* cur_s  = (int*)alloc((size_t)NS * 4);
  int* csr_p  = (int*)alloc((size_t)E * 4);
  int* csr_s  = (int*)alloc((size_t)E * 4);

  float* s2_out = (float*)d_out;
  float* p2_out = (float*)d_out + (size_t)NS * 128;

  const int eb = (E + 255) / 256;

  // ---- graph prep ----
  hipMemsetAsync(cnt_p, 0, ((size_t)NP + NS + 2) * 4, stream);
  gather_play_k<<<(NP * 32 + 255) / 256, 256, 0, stream>>>(emb, pid, x_play, NP);
  hist_k<<<eb, 256, 0, stream>>>(e_song, e_play, cnt_s, cnt_p, E);
  base_k<<<(NP + 255) / 256, 256, 0, stream>>>(cnt_p, base_p, cur_p, gcnt + 0, NP);
  base_k<<<(NS + 255) / 256, 256, 0, stream>>>(cnt_s, base_s, cur_s, gcnt + 1, NS);
  place_k<<<eb, 256, 0, stream>>>(e_song, e_play, cur_s, cur_p, csr_s, csr_p, E);

  // ---- layer 1 ----
  // p1 = relu( mean_p(song_x)@Wl1_sp + x_play@Wr1_sp + b1_sp )
  agg_mean_k<<<(NP + 3) / 4, 256, 0, stream>>>(song_x, csr_p, base_p, cnt_p, Ms, NP);
  // yp1 = x_play@Wl1_ps ; s1 = relu( mean_s(yp1) + song_x@Wr1_ps + b1_ps )
  gemm128_k<<<(NP + 63) / 64, 256, 0, stream>>>(x_play, Wl1_ps, nullptr, nullptr,
                                                nullptr, nullptr, yp, NP, 0);
  agg_mean_k<<<(NS + 3) / 4, 256, 0, stream>>>(yp, csr_s, base_s, cnt_s, As, NS);
  gemm128_k<<<(NP + 63) / 64, 256, 0, stream>>>(Ms, Wl1_sp, x_play, Wr1_sp,
                                                nullptr, b1_sp, p1, NP, 1);
  gemm128_k<<<(NS + 63) / 64, 256, 0, stream>>>(song_x, Wr1_ps, nullptr, nullptr,
                                                As, b1_ps, s1, NS, 1);

  // ---- layer 2 ----
  agg_mean_k<<<(NP + 3) / 4, 256, 0, stream>>>(s1, csr_p, base_p, cnt_p, Ms, NP);
  gemm128_k<<<(NP + 63) / 64, 256, 0, stream>>>(p1, Wl2_ps, nullptr, nullptr,
                                                nullptr, nullptr, yp, NP, 0);
  agg_mean_k<<<(NS + 3) / 4, 256, 0, stream>>>(yp, csr_s, base_s, cnt_s, As, NS);
  gemm128_k<<<(NP + 63) / 64, 256, 0, stream>>>(Ms, Wl2_sp, p1, Wr2_sp,
                                                nullptr, b2_sp, p2_out, NP, 0);
  gemm128_k<<<(NS + 63) / 64, 256, 0, stream>>>(s1, Wr2_ps, nullptr, nullptr,
                                                As, b2_ps, s2_out, NS, 0);
}

// Round 2
// 579.995 us; speedup vs baseline: 1.0706x; 1.0706x over previous
//
#include <hip/hip_runtime.h>

// ---------------------------------------------------------------------------
// 2-layer hetero GraphSAGE, bf16-MFMA edition.
//   - All intermediates bf16; accumulation (MFMA + segment-mean) in fp32.
//   - GEMM [M,128]@[128,128]: LDS-free, per-wave 16x128 strip, 16x16x32 MFMA.
//     W pre-transposed to [n][k] so both A and B frags are 16B-contiguous.
//   - CSR build per call (hist + block-scan-base + place), gather aggregation.
// ---------------------------------------------------------------------------

typedef __attribute__((ext_vector_type(8))) short bfrag;   // 8 bf16 (4 VGPRs)
typedef __attribute__((ext_vector_type(4))) float ffrag;   // 4 fp32 acc

static inline size_t ws_align(size_t x) { return (x + 255) & ~size_t(255); }

__device__ inline unsigned short f2bf(float f) {
  union { float f; unsigned int u; } v; v.f = f;
  unsigned int r = v.u + 0x7fffu + ((v.u >> 16) & 1u);   // round-nearest-even
  return (unsigned short)(r >> 16);
}
__device__ inline float bf2f(unsigned short h) {
  union { unsigned int u; float f; } v; v.u = ((unsigned int)h) << 16;
  return v.f;
}

// ---- conversions -----------------------------------------------------------

// 8 weight matrices [128k][128n] fp32 -> one bf16 buffer of [mat][n][k]
__global__ __launch_bounds__(256) void conv_w_k(
    const float* __restrict__ w0, const float* __restrict__ w1,
    const float* __restrict__ w2, const float* __restrict__ w3,
    const float* __restrict__ w4, const float* __restrict__ w5,
    const float* __restrict__ w6, const float* __restrict__ w7,
    unsigned short* __restrict__ out)
{
  int idx = blockIdx.x * 256 + threadIdx.x;       // 8*16384 total
  int m = idx >> 14, rem = idx & 16383;
  int n = rem >> 7, k = rem & 127;
  const float* ws[8] = {w0, w1, w2, w3, w4, w5, w6, w7};
  out[idx] = f2bf(ws[m][k * 128 + n]);
}

__global__ __launch_bounds__(256) void conv_songs_k(
    const float* __restrict__ in, unsigned short* __restrict__ out, int n4)
{
  int i = blockIdx.x * 256 + threadIdx.x;   // one float4 -> 4 bf16
  if (i >= n4) return;
  float4 v = ((const float4*)in)[i];
  ushort4 o;
  o.x = f2bf(v.x); o.y = f2bf(v.y); o.z = f2bf(v.z); o.w = f2bf(v.w);
  ((ushort4*)out)[i] = o;
}

__global__ __launch_bounds__(256) void gather_play_k(
    const float* __restrict__ emb, const int* __restrict__ pid,
    unsigned short* __restrict__ xp, int np)
{
  int i = blockIdx.x * 256 + threadIdx.x;   // 32 threads/row, float4 each
  int node = i >> 5, q = i & 31;
  if (node >= np) return;
  float4 v = ((const float4*)(emb + (size_t)pid[node] * 128))[q];
  ushort4 o;
  o.x = f2bf(v.x); o.y = f2bf(v.y); o.z = f2bf(v.z); o.w = f2bf(v.w);
  ((ushort4*)(xp + (size_t)node * 128))[q] = o;
}

// ---- CSR build -------------------------------------------------------------

__global__ __launch_bounds__(256) void hist_k(
    const int* __restrict__ es, const int* __restrict__ ep,
    int* __restrict__ cnt_s, int* __restrict__ cnt_p, int e)
{
  int i = blockIdx.x * 256 + threadIdx.x;
  if (i >= e) return;
  atomicAdd(&cnt_p[ep[i]], 1);
  atomicAdd(&cnt_s[es[i]], 1);
}

__global__ __launch_bounds__(256) void base_k(
    const int* __restrict__ cnt, int* __restrict__ base,
    int* __restrict__ cur, int* __restrict__ gcounter, int n)
{
  __shared__ int sh[256];
  __shared__ int bb;
  int t = threadIdx.x;
  int i = blockIdx.x * 256 + t;
  int v = (i < n) ? cnt[i] : 0;
  sh[t] = v;
  __syncthreads();
  for (int off = 1; off < 256; off <<= 1) {
    int tv = (t >= off) ? sh[t - off] : 0;
    __syncthreads();
    sh[t] += tv;
    __syncthreads();
  }
  if (t == 255) bb = atomicAdd(gcounter, sh[255]);
  __syncthreads();
  if (i < n) {
    int e = bb + sh[t] - v;
    base[i] = e;
    cur[i] = e;
  }
}

__global__ __launch_bounds__(256) void place_k(
    const int* __restrict__ es, const int* __restrict__ ep,
    int* __restrict__ cur_s, int* __restrict__ cur_p,
    int* __restrict__ csr_s, int* __restrict__ csr_p, int e)
{
  int i = blockIdx.x * 256 + threadIdx.x;
  if (i >= e) return;
  int s = es[i], p = ep[i];
  csr_p[atomicAdd(&cur_p[p], 1)] = s;
  csr_s[atomicAdd(&cur_s[s], 1)] = p;
}

// ---- aggregation (bf16 rows, fp32 accumulate) ------------------------------
// one wave per dst node; lane holds 2 bf16 (4B) of the 128-elem row.
__global__ __launch_bounds__(256) void agg_mean_k(
    const unsigned short* __restrict__ feat, const int* __restrict__ csr,
    const int* __restrict__ base, const int* __restrict__ cnt,
    unsigned short* __restrict__ out, int n)
{
  int wave = (blockIdx.x * 256 + threadIdx.x) >> 6;
  int lane = threadIdx.x & 63;
  if (wave >= n) return;
  int b = base[wave], c = cnt[wave];
  float ax = 0.f, ay = 0.f, bx = 0.f, by = 0.f;
  int i = 0;
  for (; i + 1 < c; i += 2) {
    unsigned int v0 = ((const unsigned int*)(feat + (size_t)csr[b + i] * 128))[lane];
    unsigned int v1 = ((const unsigned int*)(feat + (size_t)csr[b + i + 1] * 128))[lane];
    union { unsigned int u; float f; } lo0{v0 << 16}, hi0{v0 & 0xffff0000u},
                                       lo1{v1 << 16}, hi1{v1 & 0xffff0000u};
    ax += lo0.f; ay += hi0.f; bx += lo1.f; by += hi1.f;
  }
  if (i < c) {
    unsigned int v0 = ((const unsigned int*)(feat + (size_t)csr[b + i] * 128))[lane];
    union { unsigned int u; float f; } lo0{v0 << 16}, hi0{v0 & 0xffff0000u};
    ax += lo0.f; ay += hi0.f;
  }
  float inv = (c > 0) ? 1.0f / (float)c : 0.0f;
  unsigned int packed = (unsigned int)f2bf((ax + bx) * inv) |
                        ((unsigned int)f2bf((ay + by) * inv) << 16);
  ((unsigned int*)(out + (size_t)wave * 128))[lane] = packed;
}

// ---- MFMA GEMM -------------------------------------------------------------
// C[M,128] = act( A0@W0 (+A1@W1) (+Dadd) + bias ), K=128.
// Wt is [n][k] bf16. Block=256 (4 waves); wave owns rows [row0,row0+16).
// A frag: lane holds A[row0 + (lane&15)][k0 + (lane>>4)*8 + j], 16B contiguous.
// B frag: lane holds Wt[col][k0 + (lane>>4)*8 + j] = B[k][col], 16B contiguous.
// C/D:    lane holds C[row0 + (lane>>4)*4 + reg][j*16 + (lane&15)].
__global__ __launch_bounds__(256) void gemm_mfma_k(
    const unsigned short* __restrict__ A0, const unsigned short* __restrict__ W0t,
    const unsigned short* __restrict__ A1, const unsigned short* __restrict__ W1t,
    const unsigned short* __restrict__ Dadd, const float* __restrict__ bias,
    void* __restrict__ Cout, int M, int doRelu, int outBf16)
{
  int wave = threadIdx.x >> 6;
  int lane = threadIdx.x & 63;
  int row0 = blockIdx.x * 64 + wave * 16;
  if (row0 >= M) return;                 // M % 16 == 0, whole wave exits
  int r = lane & 15;
  int q = lane >> 4;

  ffrag acc[8];
#pragma unroll
  for (int j = 0; j < 8; j++) acc[j] = (ffrag)0.f;

  const unsigned short* Aps[2] = {A0, A1};
  const unsigned short* Wps[2] = {W0t, W1t};
#pragma unroll 1
  for (int p = 0; p < 2; p++) {
    const unsigned short* A = Aps[p];
    const unsigned short* Wt = Wps[p];
    if (!A) continue;
    const unsigned short* arow = A + (size_t)(row0 + r) * 128 + q * 8;
#pragma unroll
    for (int k0 = 0; k0 < 128; k0 += 32) {
      bfrag af = *(const bfrag*)(arow + k0);
#pragma unroll
      for (int j = 0; j < 8; j++) {
        bfrag bf = *(const bfrag*)(Wt + (size_t)(j * 16 + r) * 128 + k0 + q * 8);
        acc[j] = __builtin_amdgcn_mfma_f32_16x16x32_bf16(af, bf, acc[j], 0, 0, 0);
      }
    }
  }

  unsigned short* obf = (unsigned short*)Cout;
  float* of = (float*)Cout;
#pragma unroll
  for (int j = 0; j < 8; j++) {
    int col = j * 16 + r;
    float bv = bias ? bias[col] : 0.f;
#pragma unroll
    for (int t = 0; t < 4; t++) {
      size_t row = (size_t)(row0 + q * 4 + t);
      float v = acc[j][t] + bv;
      if (Dadd) v += bf2f(Dadd[row * 128 + col]);
      if (doRelu) v = fmaxf(v, 0.f);
      if (outBf16) obf[row * 128 + col] = f2bf(v);
      else of[row * 128 + col] = v;
    }
  }
}

// ---------------------------------------------------------------------------

extern "C" void kernel_launch(void* const* d_in, const int* in_sizes, int n_in,
                              void* d_out, int out_size, void* d_ws, size_t ws_size,
                              hipStream_t stream)
{
  const float* song_x = (const float*)d_in[0];
  const int*   pid    = (const int*)d_in[1];
  const int*   e_song = (const int*)d_in[2];
  const int*   e_play = (const int*)d_in[3];
  const float* emb    = (const float*)d_in[4];
  const float* Wl1_sp = (const float*)d_in[5];
  const float* Wr1_sp = (const float*)d_in[6];
  const float* b1_sp  = (const float*)d_in[7];
  const float* Wl1_ps = (const float*)d_in[8];
  const float* Wr1_ps = (const float*)d_in[9];
  const float* b1_ps  = (const float*)d_in[10];
  const float* Wl2_sp = (const float*)d_in[11];
  const float* Wr2_sp = (const float*)d_in[12];
  const float* b2_sp  = (const float*)d_in[13];
  const float* Wl2_ps = (const float*)d_in[14];
  const float* Wr2_ps = (const float*)d_in[15];
  const float* b2_ps  = (const float*)d_in[16];

  const int NS = in_sizes[0] / 128;
  const int NP = in_sizes[1];
  const int E  = in_sizes[2];

  typedef unsigned short u16;
  char* w = (char*)d_ws;
  auto alloc = [&](size_t bytes) { char* p = w; w += ws_align(bytes); return p; };
  u16* x_play = (u16*)alloc((size_t)NP * 128 * 2);
  u16* Ms     = (u16*)alloc((size_t)NP * 128 * 2);
  u16* yp     = (u16*)alloc((size_t)NP * 128 * 2);
  u16* p1     = (u16*)alloc((size_t)NP * 128 * 2);
  u16* As     = (u16*)alloc((size_t)NS * 128 * 2);
  u16* s1     = (u16*)alloc((size_t)NS * 128 * 2);
  u16* xs     = (u16*)alloc((size_t)NS * 128 * 2);
  u16* Wt     = (u16*)alloc((size_t)8 * 16384 * 2);   // [mat][n][k]
  int* cnt_p = (int*)alloc(((size_t)NP + NS + 2) * 4);
  int* cnt_s = cnt_p + NP;
  int* gcnt  = cnt_s + NS;
  int* base_p = (int*)alloc((size_t)NP * 4);
  int* cur_p  = (int*)alloc((size_t)NP * 4);
  int* base_s = (int*)alloc((size_t)NS * 4);
  int* cur_s  = (int*)alloc((size_t)NS * 4);
  int* csr_p  = (int*)alloc((size_t)E * 4);
  int* csr_s  = (int*)alloc((size_t)E * 4);

  float* s2_out = (float*)d_out;
  float* p2_out = (float*)d_out + (size_t)NS * 128;

  // weight order in Wt: 0 Wl1_sp, 1 Wr1_sp, 2 Wl1_ps, 3 Wr1_ps,
  //                     4 Wl2_sp, 5 Wr2_sp, 6 Wl2_ps, 7 Wr2_ps
  u16* Wt_l1sp = Wt + 0 * 16384;
  u16* Wt_r1sp = Wt + 1 * 16384;
  u16* Wt_l1ps = Wt + 2 * 16384;
  u16* Wt_r1ps = Wt + 3 * 16384;
  u16* Wt_l2sp = Wt + 4 * 16384;
  u16* Wt_r2sp = Wt + 5 * 16384;
  u16* Wt_l2ps = Wt + 6 * 16384;
  u16* Wt_r2ps = Wt + 7 * 16384;

  const int eb = (E + 255) / 256;

  // ---- prep ----
  hipMemsetAsync(cnt_p, 0, ((size_t)NP + NS + 2) * 4, stream);
  conv_w_k<<<512, 256, 0, stream>>>(Wl1_sp, Wr1_sp, Wl1_ps, Wr1_ps,
                                    Wl2_sp, Wr2_sp, Wl2_ps, Wr2_ps, Wt);
  conv_songs_k<<<((NS * 32) + 255) / 256, 256, 0, stream>>>(song_x, xs, NS * 32);
  gather_play_k<<<(NP * 32 + 255) / 256, 256, 0, stream>>>(emb, pid, x_play, NP);
  hist_k<<<eb, 256, 0, stream>>>(e_song, e_play, cnt_s, cnt_p, E);
  base_k<<<(NP + 255) / 256, 256, 0, stream>>>(cnt_p, base_p, cur_p, gcnt + 0, NP);
  base_k<<<(NS + 255) / 256, 256, 0, stream>>>(cnt_s, base_s, cur_s, gcnt + 1, NS);
  place_k<<<eb, 256, 0, stream>>>(e_song, e_play, cur_s, cur_p, csr_s, csr_p, E);

  const int gbP = (NP + 63) / 64, gbS = (NS + 63) / 64;

  // ---- layer 1 ----
  agg_mean_k<<<(NP + 3) / 4, 256, 0, stream>>>(xs, csr_p, base_p, cnt_p, Ms, NP);
  gemm_mfma_k<<<gbP, 256, 0, stream>>>(x_play, Wt_l1ps, nullptr, nullptr,
                                       nullptr, nullptr, yp, NP, 0, 1);
  agg_mean_k<<<(NS + 3) / 4, 256, 0, stream>>>(yp, csr_s, base_s, cnt_s, As, NS);
  gemm_mfma_k<<<gbP, 256, 0, stream>>>(Ms, Wt_l1sp, x_play, Wt_r1sp,
                                       nullptr, b1_sp, p1, NP, 1, 1);
  gemm_mfma_k<<<gbS, 256, 0, stream>>>(xs, Wt_r1ps, nullptr, nullptr,
                                       As, b1_ps, s1, NS, 1, 1);

  // ---- layer 2 ----
  agg_mean_k<<<(NP + 3) / 4, 256, 0, stream>>>(s1, csr_p, base_p, cnt_p, Ms, NP);
  gemm_mfma_k<<<gbP, 256, 0, stream>>>(p1, Wt_l2ps, nullptr, nullptr,
                                       nullptr, nullptr, yp, NP, 0, 1);
  agg_mean_k<<<(NS + 3) / 4, 256, 0, stream>>>(yp, csr_s, base_s, cnt_s, As, NS);
  gemm_mfma_k<<<gbP, 256, 0, stream>>>(Ms, Wt_l2sp, p1, Wt_r2sp,
                                       nullptr, b2_sp, p2_out, NP, 0, 0);
  gemm_mfma_k<<<gbS, 256, 0, stream>>>(s1, Wt_r2ps, nullptr, nullptr,
                                       As, b2_ps, s2_out, NS, 0, 0);
}

// Round 3
// 539.394 us; speedup vs baseline: 1.1512x; 1.0753x over previous
//
#include <hip/hip_runtime.h>

// ---------------------------------------------------------------------------
// 2-layer hetero GraphSAGE, bf16-MFMA, B-resident GEMM edition.
//   - GEMM [M,128]@[128,128]: whole weight matrix resident in wave registers
//     (32 bfrag = 128 VGPR), grid-stride over 16-row strips, operand-swapped
//     MFMA so epilogue stores are 8B/16B vectors (lane holds 4 consecutive cols).
//   - Aggregation fused with post-add (+bias'd GEMM result) + relu.
//   - CSR build per call (hist + block-scan-base + place).
// ---------------------------------------------------------------------------

typedef __attribute__((ext_vector_type(8))) short bfrag;   // 8 bf16 (4 VGPRs)
typedef __attribute__((ext_vector_type(4))) float ffrag;   // 4 fp32 acc
typedef unsigned short u16;
typedef unsigned int u32;

static inline size_t ws_align(size_t x) { return (x + 255) & ~size_t(255); }

__device__ inline u16 f2bf(float f) {
  union { float f; u32 u; } v; v.f = f;
  u32 r = v.u + 0x7fffu + ((v.u >> 16) & 1u);   // round-nearest-even
  return (u16)(r >> 16);
}
__device__ inline float bf_lo(u32 p) {
  union { u32 u; float f; } v; v.u = p << 16; return v.f;
}
__device__ inline float bf_hi(u32 p) {
  union { u32 u; float f; } v; v.u = p & 0xffff0000u; return v.f;
}

// ---- conversions -----------------------------------------------------------

// 8 weight matrices [128k][128n] fp32 -> bf16 [mat][n][k]
__global__ __launch_bounds__(256) void conv_w_k(
    const float* __restrict__ w0, const float* __restrict__ w1,
    const float* __restrict__ w2, const float* __restrict__ w3,
    const float* __restrict__ w4, const float* __restrict__ w5,
    const float* __restrict__ w6, const float* __restrict__ w7,
    u16* __restrict__ out)
{
  int idx = blockIdx.x * 256 + threadIdx.x;       // 8*16384 total
  int m = idx >> 14, rem = idx & 16383;
  int n = rem >> 7, k = rem & 127;
  const float* ws[8] = {w0, w1, w2, w3, w4, w5, w6, w7};
  out[idx] = f2bf(ws[m][k * 128 + n]);
}

__global__ __launch_bounds__(256) void conv_songs_k(
    const float* __restrict__ in, u16* __restrict__ out, int n4)
{
  int i = blockIdx.x * 256 + threadIdx.x;
  if (i >= n4) return;
  float4 v = ((const float4*)in)[i];
  ushort4 o;
  o.x = f2bf(v.x); o.y = f2bf(v.y); o.z = f2bf(v.z); o.w = f2bf(v.w);
  ((ushort4*)out)[i] = o;
}

__global__ __launch_bounds__(256) void gather_play_k(
    const float* __restrict__ emb, const int* __restrict__ pid,
    u16* __restrict__ xp, int np)
{
  int i = blockIdx.x * 256 + threadIdx.x;
  int node = i >> 5, q = i & 31;
  if (node >= np) return;
  float4 v = ((const float4*)(emb + (size_t)pid[node] * 128))[q];
  ushort4 o;
  o.x = f2bf(v.x); o.y = f2bf(v.y); o.z = f2bf(v.z); o.w = f2bf(v.w);
  ((ushort4*)(xp + (size_t)node * 128))[q] = o;
}

// ---- CSR build -------------------------------------------------------------

__global__ __launch_bounds__(256) void hist_k(
    const int* __restrict__ es, const int* __restrict__ ep,
    int* __restrict__ cnt_s, int* __restrict__ cnt_p, int e)
{
  int i = blockIdx.x * 256 + threadIdx.x;
  if (i >= e) return;
  atomicAdd(&cnt_p[ep[i]], 1);
  atomicAdd(&cnt_s[es[i]], 1);
}

__global__ __launch_bounds__(256) void base_k(
    const int* __restrict__ cnt, int* __restrict__ base,
    int* __restrict__ cur, int* __restrict__ gcounter, int n)
{
  __shared__ int sh[256];
  __shared__ int bb;
  int t = threadIdx.x;
  int i = blockIdx.x * 256 + t;
  int v = (i < n) ? cnt[i] : 0;
  sh[t] = v;
  __syncthreads();
  for (int off = 1; off < 256; off <<= 1) {
    int tv = (t >= off) ? sh[t - off] : 0;
    __syncthreads();
    sh[t] += tv;
    __syncthreads();
  }
  if (t == 255) bb = atomicAdd(gcounter, sh[255]);
  __syncthreads();
  if (i < n) {
    int e = bb + sh[t] - v;
    base[i] = e;
    cur[i] = e;
  }
}

__global__ __launch_bounds__(256) void place_k(
    const int* __restrict__ es, const int* __restrict__ ep,
    int* __restrict__ cur_s, int* __restrict__ cur_p,
    int* __restrict__ csr_s, int* __restrict__ csr_p, int e)
{
  int i = blockIdx.x * 256 + threadIdx.x;
  if (i >= e) return;
  int s = es[i], p = ep[i];
  csr_p[atomicAdd(&cur_p[p], 1)] = s;
  csr_s[atomicAdd(&cur_s[s], 1)] = p;
}

// ---- aggregation with fused post-add ---------------------------------------
// out[v] = act( mean_{u in csr[v]} feat[u]  (+ post[v]) )
// one wave per dst node; lane holds 2 bf16 (4B) of the 128-elem row.
__global__ __launch_bounds__(256) void agg_post_k(
    const u16* __restrict__ feat, const int* __restrict__ csr,
    const int* __restrict__ base, const int* __restrict__ cnt,
    const void* __restrict__ post, int postF32,
    void* __restrict__ out, int outF32, int doRelu, int n)
{
  int wave = (blockIdx.x * 256 + threadIdx.x) >> 6;
  int lane = threadIdx.x & 63;
  if (wave >= n) return;
  int b = base[wave], c = cnt[wave];
  float s0x = 0.f, s0y = 0.f, s1x = 0.f, s1y = 0.f;
  float s2x = 0.f, s2y = 0.f, s3x = 0.f, s3y = 0.f;
  int i = 0;
  for (; i + 4 <= c; i += 4) {
    int i0 = csr[b + i], i1 = csr[b + i + 1], i2 = csr[b + i + 2], i3 = csr[b + i + 3];
    u32 v0 = ((const u32*)(feat + (size_t)i0 * 128))[lane];
    u32 v1 = ((const u32*)(feat + (size_t)i1 * 128))[lane];
    u32 v2 = ((const u32*)(feat + (size_t)i2 * 128))[lane];
    u32 v3 = ((const u32*)(feat + (size_t)i3 * 128))[lane];
    s0x += bf_lo(v0); s0y += bf_hi(v0);
    s1x += bf_lo(v1); s1y += bf_hi(v1);
    s2x += bf_lo(v2); s2y += bf_hi(v2);
    s3x += bf_lo(v3); s3y += bf_hi(v3);
  }
  for (; i < c; i++) {
    u32 v0 = ((const u32*)(feat + (size_t)csr[b + i] * 128))[lane];
    s0x += bf_lo(v0); s0y += bf_hi(v0);
  }
  float inv = (c > 0) ? 1.0f / (float)c : 0.0f;
  float rx = ((s0x + s1x) + (s2x + s3x)) * inv;
  float ry = ((s0y + s1y) + (s2y + s3y)) * inv;
  size_t ei = (size_t)wave * 64 + lane;
  if (post) {
    if (postF32) {
      float2 p = ((const float2*)post)[ei];
      rx += p.x; ry += p.y;
    } else {
      u32 p = ((const u32*)post)[ei];
      rx += bf_lo(p); ry += bf_hi(p);
    }
  }
  if (doRelu) { rx = fmaxf(rx, 0.f); ry = fmaxf(ry, 0.f); }
  if (outF32) {
    ((float2*)out)[ei] = make_float2(rx, ry);
  } else {
    ((u32*)out)[ei] = (u32)f2bf(rx) | ((u32)f2bf(ry) << 16);
  }
}

// ---- B-resident MFMA GEMM --------------------------------------------------
// C[M,128] = act( A@W (+Dadd_f32) (+bias) ), K=128, Wt = [n][k] bf16.
// Wave holds ALL of W in registers (32 bfrags = 128 VGPR), grid-strides over
// 16-row strips. Operand-swapped MFMA: D' = (A@B)^T per tile, so lane holds
// C[row = lane&15][col = j*16 + (lane>>4)*4 + t] -> 4 consecutive cols
// (8B bf16 / 16B fp32 vector stores).
__global__ __launch_bounds__(256, 2) void gemm_breg_k(
    const u16* __restrict__ A, const u16* __restrict__ Wt,
    const float* __restrict__ bias, const float* __restrict__ Dadd,
    void* __restrict__ Cout, int M, int doRelu, int outF32)
{
  int lane = threadIdx.x & 63;
  int r = lane & 15, q = lane >> 4;
  int wid = (blockIdx.x * 256 + threadIdx.x) >> 6;
  int nw = gridDim.x * 4;

  // B fragment [k0][j]: lane holds Wt[j*16 + r][k0*32 + q*8 .. +7]
  bfrag B[4][8];
#pragma unroll
  for (int k0 = 0; k0 < 4; k0++)
#pragma unroll
    for (int j = 0; j < 8; j++)
      B[k0][j] = *(const bfrag*)(Wt + (size_t)(j * 16 + r) * 128 + k0 * 32 + q * 8);

  for (int strip = wid; strip * 16 < M; strip += nw) {
    const u16* arow = A + (size_t)(strip * 16 + r) * 128 + q * 8;
    bfrag a0 = *(const bfrag*)(arow);
    bfrag a1 = *(const bfrag*)(arow + 32);
    bfrag a2 = *(const bfrag*)(arow + 64);
    bfrag a3 = *(const bfrag*)(arow + 96);

    ffrag acc[8];
#pragma unroll
    for (int j = 0; j < 8; j++) acc[j] = (ffrag)0.f;
#pragma unroll
    for (int j = 0; j < 8; j++)
      acc[j] = __builtin_amdgcn_mfma_f32_16x16x32_bf16(B[0][j], a0, acc[j], 0, 0, 0);
#pragma unroll
    for (int j = 0; j < 8; j++)
      acc[j] = __builtin_amdgcn_mfma_f32_16x16x32_bf16(B[1][j], a1, acc[j], 0, 0, 0);
#pragma unroll
    for (int j = 0; j < 8; j++)
      acc[j] = __builtin_amdgcn_mfma_f32_16x16x32_bf16(B[2][j], a2, acc[j], 0, 0, 0);
#pragma unroll
    for (int j = 0; j < 8; j++)
      acc[j] = __builtin_amdgcn_mfma_f32_16x16x32_bf16(B[3][j], a3, acc[j], 0, 0, 0);

    size_t row = (size_t)(strip * 16 + r);
#pragma unroll
    for (int j = 0; j < 8; j++) {
      int col0 = j * 16 + q * 4;
      float v0 = acc[j][0], v1 = acc[j][1], v2 = acc[j][2], v3 = acc[j][3];
      if (bias) {
        float4 bv = *(const float4*)(bias + col0);
        v0 += bv.x; v1 += bv.y; v2 += bv.z; v3 += bv.w;
      }
      if (Dadd) {
        float4 dv = *(const float4*)(Dadd + row * 128 + col0);
        v0 += dv.x; v1 += dv.y; v2 += dv.z; v3 += dv.w;
      }
      if (doRelu) {
        v0 = fmaxf(v0, 0.f); v1 = fmaxf(v1, 0.f);
        v2 = fmaxf(v2, 0.f); v3 = fmaxf(v3, 0.f);
      }
      if (outF32) {
        *(float4*)((float*)Cout + row * 128 + col0) = make_float4(v0, v1, v2, v3);
      } else {
        ushort4 o;
        o.x = f2bf(v0); o.y = f2bf(v1); o.z = f2bf(v2); o.w = f2bf(v3);
        *(ushort4*)((u16*)Cout + row * 128 + col0) = o;
      }
    }
  }
}

// ---------------------------------------------------------------------------

extern "C" void kernel_launch(void* const* d_in, const int* in_sizes, int n_in,
                              void* d_out, int out_size, void* d_ws, size_t ws_size,
                              hipStream_t stream)
{
  const float* song_x = (const float*)d_in[0];
  const int*   pid    = (const int*)d_in[1];
  const int*   e_song = (const int*)d_in[2];
  const int*   e_play = (const int*)d_in[3];
  const float* emb    = (const float*)d_in[4];
  const float* Wl1_sp = (const float*)d_in[5];
  const float* Wr1_sp = (const float*)d_in[6];
  const float* b1_sp  = (const float*)d_in[7];
  const float* Wl1_ps = (const float*)d_in[8];
  const float* Wr1_ps = (const float*)d_in[9];
  const float* b1_ps  = (const float*)d_in[10];
  const float* Wl2_sp = (const float*)d_in[11];
  const float* Wr2_sp = (const float*)d_in[12];
  const float* b2_sp  = (const float*)d_in[13];
  const float* Wl2_ps = (const float*)d_in[14];
  const float* Wr2_ps = (const float*)d_in[15];
  const float* b2_ps  = (const float*)d_in[16];

  const int NS = in_sizes[0] / 128;
  const int NP = in_sizes[1];
  const int E  = in_sizes[2];

  char* w = (char*)d_ws;
  auto alloc = [&](size_t bytes) { char* p = w; w += ws_align(bytes); return p; };
  u16* x_play = (u16*)alloc((size_t)NP * 128 * 2);
  u16* Ms     = (u16*)alloc((size_t)NP * 128 * 2);
  u16* yp     = (u16*)alloc((size_t)NP * 128 * 2);
  u16* p1     = (u16*)alloc((size_t)NP * 128 * 2);
  u16* s1     = (u16*)alloc((size_t)NS * 128 * 2);
  u16* xs     = (u16*)alloc((size_t)NS * 128 * 2);
  float* Gs   = (float*)alloc((size_t)NS * 128 * 4);  // bf16 in L1, fp32 in L2
  float* Gp   = (float*)alloc((size_t)NP * 128 * 4);
  u16* Wt     = (u16*)alloc((size_t)8 * 16384 * 2);   // [mat][n][k]
  int* cnt_p = (int*)alloc(((size_t)NP + NS + 2) * 4);
  int* cnt_s = cnt_p + NP;
  int* gcnt  = cnt_s + NS;
  int* base_p = (int*)alloc((size_t)NP * 4);
  int* cur_p  = (int*)alloc((size_t)NP * 4);
  int* base_s = (int*)alloc((size_t)NS * 4);
  int* cur_s  = (int*)alloc((size_t)NS * 4);
  int* csr_p  = (int*)alloc((size_t)E * 4);
  int* csr_s  = (int*)alloc((size_t)E * 4);

  float* s2_out = (float*)d_out;
  float* p2_out = (float*)d_out + (size_t)NS * 128;

  u16* Wt_l1sp = Wt + 0 * 16384;
  u16* Wt_r1sp = Wt + 1 * 16384;
  u16* Wt_l1ps = Wt + 2 * 16384;
  u16* Wt_r1ps = Wt + 3 * 16384;
  u16* Wt_l2sp = Wt + 4 * 16384;
  u16* Wt_r2sp = Wt + 5 * 16384;
  u16* Wt_l2ps = Wt + 6 * 16384;
  u16* Wt_r2ps = Wt + 7 * 16384;

  const int eb = (E + 255) / 256;
  // gemm grid: ~4 strips per wave
  auto ggrid = [](int M) { int s = M / 16; return (s + 15) / 16; };
  const int gS = ggrid(NS), gP = ggrid(NP);
  const int aggP_b = (NP + 3) / 4, aggS_b = (NS + 3) / 4;

  // ---- prep ----
  hipMemsetAsync(cnt_p, 0, ((size_t)NP + NS + 2) * 4, stream);
  conv_w_k<<<512, 256, 0, stream>>>(Wl1_sp, Wr1_sp, Wl1_ps, Wr1_ps,
                                    Wl2_sp, Wr2_sp, Wl2_ps, Wr2_ps, Wt);
  conv_songs_k<<<((NS * 32) + 255) / 256, 256, 0, stream>>>(song_x, xs, NS * 32);
  gather_play_k<<<(NP * 32 + 255) / 256, 256, 0, stream>>>(emb, pid, x_play, NP);
  hist_k<<<eb, 256, 0, stream>>>(e_song, e_play, cnt_s, cnt_p, E);
  base_k<<<(NP + 255) / 256, 256, 0, stream>>>(cnt_p, base_p, cur_p, gcnt + 0, NP);
  base_k<<<(NS + 255) / 256, 256, 0, stream>>>(cnt_s, base_s, cur_s, gcnt + 1, NS);
  place_k<<<eb, 256, 0, stream>>>(e_song, e_play, cur_s, cur_p, csr_s, csr_p, E);

  // ---- layer 1 ----
  // Ms = mean_p(xs)
  agg_post_k<<<aggP_b, 256, 0, stream>>>(xs, csr_p, base_p, cnt_p,
                                         nullptr, 0, Ms, 0, 0, NP);
  // yp = x_play@Wl1_ps (no bias; bias folded into song-side G)
  gemm_breg_k<<<gP, 256, 0, stream>>>(x_play, Wt_l1ps, nullptr, nullptr,
                                      yp, NP, 0, 0);
  // G1s = xs@Wr1_ps + b1_ps (bf16)
  gemm_breg_k<<<gS, 256, 0, stream>>>(xs, Wt_r1ps, b1_ps, nullptr,
                                      (void*)Gs, NS, 0, 0);
  // s1 = relu(mean_s(yp) + G1s)
  agg_post_k<<<aggS_b, 256, 0, stream>>>(yp, csr_s, base_s, cnt_s,
                                         (void*)Gs, 0, s1, 0, 1, NS);
  // Gp = Ms@Wl1_sp (fp32)
  gemm_breg_k<<<gP, 256, 0, stream>>>(Ms, Wt_l1sp, nullptr, nullptr,
                                      (void*)Gp, NP, 0, 1);
  // p1 = relu(x_play@Wr1_sp + b1_sp + Gp)
  gemm_breg_k<<<gP, 256, 0, stream>>>(x_play, Wt_r1sp, b1_sp, Gp,
                                      p1, NP, 1, 0);

  // ---- layer 2 ----
  // Ms = mean_p(s1)
  agg_post_k<<<aggP_b, 256, 0, stream>>>(s1, csr_p, base_p, cnt_p,
                                         nullptr, 0, Ms, 0, 0, NP);
  // yp = p1@Wl2_ps
  gemm_breg_k<<<gP, 256, 0, stream>>>(p1, Wt_l2ps, nullptr, nullptr,
                                      yp, NP, 0, 0);
  // G2s = s1@Wr2_ps + b2_ps (fp32 for final accuracy)
  gemm_breg_k<<<gS, 256, 0, stream>>>(s1, Wt_r2ps, b2_ps, nullptr,
                                      (void*)Gs, NS, 0, 1);
  // s2 = mean_s(yp) + G2s  (fp32 out)
  agg_post_k<<<aggS_b, 256, 0, stream>>>(yp, csr_s, base_s, cnt_s,
                                         (void*)Gs, 1, s2_out, 1, 0, NS);
  // Gp = Ms@Wl2_sp (fp32)
  gemm_breg_k<<<gP, 256, 0, stream>>>(Ms, Wt_l2sp, nullptr, nullptr,
                                      (void*)Gp, NP, 0, 1);
  // p2 = p1@Wr2_sp + b2_sp + Gp (fp32 out)
  gemm_breg_k<<<gP, 256, 0, stream>>>(p1, Wt_r2sp, b2_sp, Gp,
                                      p2_out, NP, 0, 1);
}

// Round 4
// 523.459 us; speedup vs baseline: 1.1862x; 1.0304x over previous
//
#include <hip/hip_runtime.h>

// ---------------------------------------------------------------------------
// 2-layer hetero GraphSAGE, bf16-MFMA, XCD-chunked CSR build.
//   - CSR scatter + histogram are chunked by destination range with chunk id
//     = blockIdx&7 (round-robin block->XCD map), so every CSR line / counter
//     is written by exactly ONE XCD -> no cross-XCD partial-line HBM RMW.
//   - GEMM: weight matrix resident in wave registers, operand-swapped MFMA,
//     vectorized epilogue (R3).
//   - Aggregation gather fused with post-add (+relu), 8-deep MLP unroll.
// ---------------------------------------------------------------------------

typedef __attribute__((ext_vector_type(8))) short bfrag;   // 8 bf16 (4 VGPRs)
typedef __attribute__((ext_vector_type(4))) float ffrag;   // 4 fp32 acc
typedef unsigned short u16;
typedef unsigned int u32;

static inline size_t ws_align(size_t x) { return (x + 255) & ~size_t(255); }

__device__ inline u16 f2bf(float f) {
  union { float f; u32 u; } v; v.f = f;
  u32 r = v.u + 0x7fffu + ((v.u >> 16) & 1u);   // round-nearest-even
  return (u16)(r >> 16);
}
__device__ inline float bf_lo(u32 p) {
  union { u32 u; float f; } v; v.u = p << 16; return v.f;
}
__device__ inline float bf_hi(u32 p) {
  union { u32 u; float f; } v; v.u = p & 0xffff0000u; return v.f;
}

// ---- fused prep: zero counters, conv weights, conv songs, gather playlists -
__global__ __launch_bounds__(256) void prep_k(
    const float* __restrict__ w0, const float* __restrict__ w1,
    const float* __restrict__ w2, const float* __restrict__ w3,
    const float* __restrict__ w4, const float* __restrict__ w5,
    const float* __restrict__ w6, const float* __restrict__ w7,
    u16* __restrict__ Wt,
    const float* __restrict__ song_x, u16* __restrict__ xs, int ns4,
    const float* __restrict__ emb, const int* __restrict__ pid,
    u16* __restrict__ xp, int np,
    int* __restrict__ zero_region, int nzero)
{
  int g0 = blockIdx.x * 256 + threadIdx.x;
  int gs = gridDim.x * 256;
  // zero counters
  for (int i = g0; i < nzero; i += gs) zero_region[i] = 0;
  // weights: 8 * 16384, [mat][n][k] <- [k][n]
  const float* ws[8] = {w0, w1, w2, w3, w4, w5, w6, w7};
  for (int idx = g0; idx < 8 * 16384; idx += gs) {
    int m = idx >> 14, rem = idx & 16383;
    int n = rem >> 7, k = rem & 127;
    Wt[idx] = f2bf(ws[m][k * 128 + n]);
  }
  // songs fp32 -> bf16 (float4 granules)
  for (int i = g0; i < ns4; i += gs) {
    float4 v = ((const float4*)song_x)[i];
    ushort4 o;
    o.x = f2bf(v.x); o.y = f2bf(v.y); o.z = f2bf(v.z); o.w = f2bf(v.w);
    ((ushort4*)xs)[i] = o;
  }
  // playlist embed gather (32 float4 per row)
  for (int i = g0; i < np * 32; i += gs) {
    int node = i >> 5, q = i & 31;
    float4 v = ((const float4*)(emb + (size_t)pid[node] * 128))[q];
    ushort4 o;
    o.x = f2bf(v.x); o.y = f2bf(v.y); o.z = f2bf(v.z); o.w = f2bf(v.w);
    ((ushort4*)(xp + (size_t)node * 128))[q] = o;
  }
}

// ---- CSR build (XCD-chunked) ----------------------------------------------
// chunk j = blockIdx&7 handles dst range [j*chunk, (j+1)*chunk) of each side.
__global__ __launch_bounds__(256) void hist_k(
    const int* __restrict__ es, const int* __restrict__ ep,
    int* __restrict__ cnt_s, int* __restrict__ cnt_p,
    int e, int pch, int sch)
{
  int j = blockIdx.x & 7;
  int g = blockIdx.x >> 3;
  int nb = gridDim.x >> 3;
  int p_lo = j * pch, s_lo = j * sch;
  for (int i = g * 256 + threadIdx.x; i < e; i += nb * 256) {
    int p = ep[i], s = es[i];
    if ((u32)(p - p_lo) < (u32)pch) atomicAdd(&cnt_p[p], 1);
    if ((u32)(s - s_lo) < (u32)sch) atomicAdd(&cnt_s[s], 1);
  }
}

// dual-segment exclusive scan: blocks [0, nbp) cover cnt_p, rest cover cnt_s.
__global__ __launch_bounds__(256) void base2_k(
    const int* __restrict__ cnt_p, int* __restrict__ base_p, int* __restrict__ cur_p,
    const int* __restrict__ cnt_s, int* __restrict__ base_s, int* __restrict__ cur_s,
    int* __restrict__ gcnt, int np, int ns, int nbp)
{
  __shared__ int sh[256];
  __shared__ int bb;
  int t = threadIdx.x;
  const int* cnt; int* base; int* cur; int* gc; int n; int i;
  if ((int)blockIdx.x < nbp) {
    cnt = cnt_p; base = base_p; cur = cur_p; gc = gcnt; n = np;
    i = blockIdx.x * 256 + t;
  } else {
    cnt = cnt_s; base = base_s; cur = cur_s; gc = gcnt + 1; n = ns;
    i = (blockIdx.x - nbp) * 256 + t;
  }
  int v = (i < n) ? cnt[i] : 0;
  sh[t] = v;
  __syncthreads();
  for (int off = 1; off < 256; off <<= 1) {
    int tv = (t >= off) ? sh[t - off] : 0;
    __syncthreads();
    sh[t] += tv;
    __syncthreads();
  }
  if (t == 255) bb = atomicAdd(gc, sh[255]);
  __syncthreads();
  if (i < n) {
    int e = bb + sh[t] - v;
    base[i] = e;
    cur[i] = e;
  }
}

__global__ __launch_bounds__(256) void place_k(
    const int* __restrict__ es, const int* __restrict__ ep,
    int* __restrict__ cur_s, int* __restrict__ cur_p,
    int* __restrict__ csr_s, int* __restrict__ csr_p,
    int e, int pch, int sch)
{
  int j = blockIdx.x & 7;
  int g = blockIdx.x >> 3;
  int nb = gridDim.x >> 3;
  int p_lo = j * pch, s_lo = j * sch;
  for (int i = g * 256 + threadIdx.x; i < e; i += nb * 256) {
    int p = ep[i], s = es[i];
    if ((u32)(p - p_lo) < (u32)pch) csr_p[atomicAdd(&cur_p[p], 1)] = s;
    if ((u32)(s - s_lo) < (u32)sch) csr_s[atomicAdd(&cur_s[s], 1)] = p;
  }
}

// ---- aggregation with fused post-add ---------------------------------------
// out[v] = act( mean_{u in csr[v]} feat[u]  (+ post[v]) )
// one wave per dst node; lane holds 2 bf16 (4B) of the 128-elem row.
__global__ __launch_bounds__(256) void agg_post_k(
    const u16* __restrict__ feat, const int* __restrict__ csr,
    const int* __restrict__ base, const int* __restrict__ cnt,
    const void* __restrict__ post, int postF32,
    void* __restrict__ out, int outF32, int doRelu, int n)
{
  int wave = (blockIdx.x * 256 + threadIdx.x) >> 6;
  int lane = threadIdx.x & 63;
  if (wave >= n) return;
  int b = base[wave], c = cnt[wave];
  float sx[8] = {0.f,0.f,0.f,0.f,0.f,0.f,0.f,0.f};
  float sy[8] = {0.f,0.f,0.f,0.f,0.f,0.f,0.f,0.f};
  int i = 0;
  for (; i + 8 <= c; i += 8) {
    int idx[8];
#pragma unroll
    for (int u = 0; u < 8; u++) idx[u] = csr[b + i + u];
#pragma unroll
    for (int u = 0; u < 8; u++) {
      u32 v = ((const u32*)(feat + (size_t)idx[u] * 128))[lane];
      sx[u] += bf_lo(v); sy[u] += bf_hi(v);
    }
  }
  for (; i < c; i++) {
    u32 v = ((const u32*)(feat + (size_t)csr[b + i] * 128))[lane];
    sx[0] += bf_lo(v); sy[0] += bf_hi(v);
  }
  float rx = ((sx[0]+sx[1]) + (sx[2]+sx[3])) + ((sx[4]+sx[5]) + (sx[6]+sx[7]));
  float ry = ((sy[0]+sy[1]) + (sy[2]+sy[3])) + ((sy[4]+sy[5]) + (sy[6]+sy[7]));
  float inv = (c > 0) ? 1.0f / (float)c : 0.0f;
  rx *= inv; ry *= inv;
  size_t ei = (size_t)wave * 64 + lane;
  if (post) {
    if (postF32) {
      float2 p = ((const float2*)post)[ei];
      rx += p.x; ry += p.y;
    } else {
      u32 p = ((const u32*)post)[ei];
      rx += bf_lo(p); ry += bf_hi(p);
    }
  }
  if (doRelu) { rx = fmaxf(rx, 0.f); ry = fmaxf(ry, 0.f); }
  if (outF32) {
    ((float2*)out)[ei] = make_float2(rx, ry);
  } else {
    ((u32*)out)[ei] = (u32)f2bf(rx) | ((u32)f2bf(ry) << 16);
  }
}

// ---- B-resident MFMA GEMM --------------------------------------------------
// C[M,128] = act( A@W (+Dadd_f32) (+bias) ), K=128, Wt = [n][k] bf16.
// Wave holds all of W in registers (32 bfrags = 128 VGPR), grid-strides over
// 16-row strips. Operand-swapped MFMA -> lane holds 4 consecutive cols.
__global__ __launch_bounds__(256, 2) void gemm_breg_k(
    const u16* __restrict__ A, const u16* __restrict__ Wt,
    const float* __restrict__ bias, const float* __restrict__ Dadd,
    void* __restrict__ Cout, int M, int doRelu, int outF32)
{
  int lane = threadIdx.x & 63;
  int r = lane & 15, q = lane >> 4;
  int wid = (blockIdx.x * 256 + threadIdx.x) >> 6;
  int nw = gridDim.x * 4;

  bfrag B[4][8];
#pragma unroll
  for (int k0 = 0; k0 < 4; k0++)
#pragma unroll
    for (int j = 0; j < 8; j++)
      B[k0][j] = *(const bfrag*)(Wt + (size_t)(j * 16 + r) * 128 + k0 * 32 + q * 8);

  for (int strip = wid; strip * 16 < M; strip += nw) {
    const u16* arow = A + (size_t)(strip * 16 + r) * 128 + q * 8;
    bfrag a0 = *(const bfrag*)(arow);
    bfrag a1 = *(const bfrag*)(arow + 32);
    bfrag a2 = *(const bfrag*)(arow + 64);
    bfrag a3 = *(const bfrag*)(arow + 96);

    ffrag acc[8];
#pragma unroll
    for (int j = 0; j < 8; j++) acc[j] = (ffrag)0.f;
#pragma unroll
    for (int j = 0; j < 8; j++)
      acc[j] = __builtin_amdgcn_mfma_f32_16x16x32_bf16(B[0][j], a0, acc[j], 0, 0, 0);
#pragma unroll
    for (int j = 0; j < 8; j++)
      acc[j] = __builtin_amdgcn_mfma_f32_16x16x32_bf16(B[1][j], a1, acc[j], 0, 0, 0);
#pragma unroll
    for (int j = 0; j < 8; j++)
      acc[j] = __builtin_amdgcn_mfma_f32_16x16x32_bf16(B[2][j], a2, acc[j], 0, 0, 0);
#pragma unroll
    for (int j = 0; j < 8; j++)
      acc[j] = __builtin_amdgcn_mfma_f32_16x16x32_bf16(B[3][j], a3, acc[j], 0, 0, 0);

    size_t row = (size_t)(strip * 16 + r);
#pragma unroll
    for (int j = 0; j < 8; j++) {
      int col0 = j * 16 + q * 4;
      float v0 = acc[j][0], v1 = acc[j][1], v2 = acc[j][2], v3 = acc[j][3];
      if (bias) {
        float4 bv = *(const float4*)(bias + col0);
        v0 += bv.x; v1 += bv.y; v2 += bv.z; v3 += bv.w;
      }
      if (Dadd) {
        float4 dv = *(const float4*)(Dadd + row * 128 + col0);
        v0 += dv.x; v1 += dv.y; v2 += dv.z; v3 += dv.w;
      }
      if (doRelu) {
        v0 = fmaxf(v0, 0.f); v1 = fmaxf(v1, 0.f);
        v2 = fmaxf(v2, 0.f); v3 = fmaxf(v3, 0.f);
      }
      if (outF32) {
        *(float4*)((float*)Cout + row * 128 + col0) = make_float4(v0, v1, v2, v3);
      } else {
        ushort4 o;
        o.x = f2bf(v0); o.y = f2bf(v1); o.z = f2bf(v2); o.w = f2bf(v3);
        *(ushort4*)((u16*)Cout + row * 128 + col0) = o;
      }
    }
  }
}

// ---------------------------------------------------------------------------

extern "C" void kernel_launch(void* const* d_in, const int* in_sizes, int n_in,
                              void* d_out, int out_size, void* d_ws, size_t ws_size,
                              hipStream_t stream)
{
  const float* song_x = (const float*)d_in[0];
  const int*   pid    = (const int*)d_in[1];
  const int*   e_song = (const int*)d_in[2];
  const int*   e_play = (const int*)d_in[3];
  const float* emb    = (const float*)d_in[4];
  const float* Wl1_sp = (const float*)d_in[5];
  const float* Wr1_sp = (const float*)d_in[6];
  const float* b1_sp  = (const float*)d_in[7];
  const float* Wl1_ps = (const float*)d_in[8];
  const float* Wr1_ps = (const float*)d_in[9];
  const float* b1_ps  = (const float*)d_in[10];
  const float* Wl2_sp = (const float*)d_in[11];
  const float* Wr2_sp = (const float*)d_in[12];
  const float* b2_sp  = (const float*)d_in[13];
  const float* Wl2_ps = (const float*)d_in[14];
  const float* Wr2_ps = (const float*)d_in[15];
  const float* b2_ps  = (const float*)d_in[16];

  const int NS = in_sizes[0] / 128;
  const int NP = in_sizes[1];
  const int E  = in_sizes[2];

  char* w = (char*)d_ws;
  auto alloc = [&](size_t bytes) { char* p = w; w += ws_align(bytes); return p; };
  u16* x_play = (u16*)alloc((size_t)NP * 128 * 2);
  u16* Ms     = (u16*)alloc((size_t)NP * 128 * 2);
  u16* yp     = (u16*)alloc((size_t)NP * 128 * 2);
  u16* p1     = (u16*)alloc((size_t)NP * 128 * 2);
  u16* s1     = (u16*)alloc((size_t)NS * 128 * 2);
  u16* xs     = (u16*)alloc((size_t)NS * 128 * 2);
  u16* Gs     = (u16*)alloc((size_t)NS * 128 * 2);   // bf16 both layers
  float* Gp   = (float*)alloc((size_t)NP * 128 * 4);
  u16* Wt     = (u16*)alloc((size_t)8 * 16384 * 2);  // [mat][n][k]
  int* cnt_p = (int*)alloc(((size_t)NP + NS + 2) * 4);
  int* cnt_s = cnt_p + NP;
  int* gcnt  = cnt_s + NS;
  int* base_p = (int*)alloc((size_t)NP * 4);
  int* cur_p  = (int*)alloc((size_t)NP * 4);
  int* base_s = (int*)alloc((size_t)NS * 4);
  int* cur_s  = (int*)alloc((size_t)NS * 4);
  int* csr_p  = (int*)alloc((size_t)E * 4);
  int* csr_s  = (int*)alloc((size_t)E * 4);

  float* s2_out = (float*)d_out;
  float* p2_out = (float*)d_out + (size_t)NS * 128;

  u16* Wt_l1sp = Wt + 0 * 16384;
  u16* Wt_r1sp = Wt + 1 * 16384;
  u16* Wt_l1ps = Wt + 2 * 16384;
  u16* Wt_r1ps = Wt + 3 * 16384;
  u16* Wt_l2sp = Wt + 4 * 16384;
  u16* Wt_r2sp = Wt + 5 * 16384;
  u16* Wt_l2ps = Wt + 6 * 16384;
  u16* Wt_r2ps = Wt + 7 * 16384;

  const int pch = (NP + 7) / 8, sch = (NS + 7) / 8;
  const int edge_grid = 8 * 104;   // chunk = blockIdx&7 -> XCD-local scatter
  auto ggrid = [](int M) { int s = M / 16; return (s + 7) / 8; };  // ~2 strips/wave
  const int gS = ggrid(NS), gP = ggrid(NP);
  const int aggP_b = (NP + 3) / 4, aggS_b = (NS + 3) / 4;
  const int nbp = (NP + 255) / 256, nbs = (NS + 255) / 256;

  // ---- prep + CSR build ----
  prep_k<<<1024, 256, 0, stream>>>(Wl1_sp, Wr1_sp, Wl1_ps, Wr1_ps,
                                   Wl2_sp, Wr2_sp, Wl2_ps, Wr2_ps, Wt,
                                   song_x, xs, NS * 32,
                                   emb, pid, x_play, NP,
                                   cnt_p, NP + NS + 2);
  hist_k<<<edge_grid, 256, 0, stream>>>(e_song, e_play, cnt_s, cnt_p, E, pch, sch);
  base2_k<<<nbp + nbs, 256, 0, stream>>>(cnt_p, base_p, cur_p,
                                         cnt_s, base_s, cur_s, gcnt, NP, NS, nbp);
  place_k<<<edge_grid, 256, 0, stream>>>(e_song, e_play, cur_s, cur_p,
                                         csr_s, csr_p, E, pch, sch);

  // ---- layer 1 ----
  // Ms = mean_p(xs)
  agg_post_k<<<aggP_b, 256, 0, stream>>>(xs, csr_p, base_p, cnt_p,
                                         nullptr, 0, Ms, 0, 0, NP);
  // yp = x_play@Wl1_ps
  gemm_breg_k<<<gP, 256, 0, stream>>>(x_play, Wt_l1ps, nullptr, nullptr,
                                      yp, NP, 0, 0);
  // G1s = xs@Wr1_ps + b1_ps (bf16)
  gemm_breg_k<<<gS, 256, 0, stream>>>(xs, Wt_r1ps, b1_ps, nullptr,
                                      (void*)Gs, NS, 0, 0);
  // s1 = relu(mean_s(yp) + G1s)
  agg_post_k<<<aggS_b, 256, 0, stream>>>(yp, csr_s, base_s, cnt_s,
                                         (void*)Gs, 0, s1, 0, 1, NS);
  // Gp = Ms@Wl1_sp (fp32)
  gemm_breg_k<<<gP, 256, 0, stream>>>(Ms, Wt_l1sp, nullptr, nullptr,
                                      (void*)Gp, NP, 0, 1);
  // p1 = relu(x_play@Wr1_sp + b1_sp + Gp)
  gemm_breg_k<<<gP, 256, 0, stream>>>(x_play, Wt_r1sp, b1_sp, Gp,
                                      p1, NP, 1, 0);

  // ---- layer 2 ----
  // Ms = mean_p(s1)
  agg_post_k<<<aggP_b, 256, 0, stream>>>(s1, csr_p, base_p, cnt_p,
                                         nullptr, 0, Ms, 0, 0, NP);
  // yp = p1@Wl2_ps
  gemm_breg_k<<<gP, 256, 0, stream>>>(p1, Wt_l2ps, nullptr, nullptr,
                                      yp, NP, 0, 0);
  // G2s = s1@Wr2_ps + b2_ps (bf16)
  gemm_breg_k<<<gS, 256, 0, stream>>>(s1, Wt_r2ps, b2_ps, nullptr,
                                      (void*)Gs, NS, 0, 0);
  // s2 = mean_s(yp) + G2s  (fp32 out)
  agg_post_k<<<aggS_b, 256, 0, stream>>>(yp, csr_s, base_s, cnt_s,
                                         (void*)Gs, 0, s2_out, 1, 0, NS);
  // Gp = Ms@Wl2_sp (fp32)
  gemm_breg_k<<<gP, 256, 0, stream>>>(Ms, Wt_l2sp, nullptr, nullptr,
                                      (void*)Gp, NP, 0, 1);
  // p2 = p1@Wr2_sp + b2_sp + Gp (fp32 out)
  gemm_breg_k<<<gP, 256, 0, stream>>>(p1, Wt_r2sp, b2_sp, Gp,
                                      p2_out, NP, 0, 1);
}